// Round 5
// baseline (181.528 us; speedup 1.0000x reference)
//
#include <hip/hip_runtime.h>

#define BB 2
#define NN 16
#define LQ 512
#define DKk 64
#define DVv 64
#define DDd 128
#define H2 256
#define NEG_INF -1e9f
#define CAP 131072

// ---------------------------------------------------------------------------
// Stage 1 v2: 2 rows per block, grid 1024, 4 blocks/CU, 16 waves/CU.
// Per-(row,g) fp64 chain unchanged -> bit-identical U/W outputs.
// Block 0 thread 0 also zeroes the ambiguous-pair counter.
// ---------------------------------------------------------------------------
__global__ __launch_bounds__(256) void mlp_stage1(
    const float* __restrict__ d0, const float* __restrict__ d1,
    const float* __restrict__ W1, const float* __restrict__ b1,
    double* __restrict__ U64, double* __restrict__ W64,
    float* __restrict__ U32, float* __restrict__ W32,
    int* __restrict__ count)
{
    __shared__ float drow[2][DDd];
    int gid = blockIdx.x;            // half(2) x rowgroup(512)
    int half = gid >> 9;
    int r0 = (gid & 511) * 2;        // rows r0..r0+1 of 1024
    const float* din = half ? d1 : d0;
    int w1off = half ? DDd : 0;
    double* o64 = half ? W64 : U64;
    float* o32 = half ? W32 : U32;
    int t = threadIdx.x;
    if (gid == 0 && t == 0) *count = 0;
    drow[t >> 7][t & 127] = din[(size_t)(r0 + (t >> 7)) * DDd + (t & 127)];
    __syncthreads();
    int g = t;
    double acc[2] = {};
#pragma unroll 2
    for (int f = 0; f < DDd; f += 4) {
        double w0 = (double)W1[(w1off + f + 0) * H2 + g];
        double w1 = (double)W1[(w1off + f + 1) * H2 + g];
        double w2 = (double)W1[(w1off + f + 2) * H2 + g];
        double w3 = (double)W1[(w1off + f + 3) * H2 + g];
#pragma unroll
        for (int r = 0; r < 2; ++r) {
            float4 dr = *(const float4*)&drow[r][f];
            acc[r] = fma((double)dr.x, w0, acc[r]);
            acc[r] = fma((double)dr.y, w1, acc[r]);
            acc[r] = fma((double)dr.z, w2, acc[r]);
            acc[r] = fma((double)dr.w, w3, acc[r]);
        }
    }
    double bb = half ? 0.0 : (double)b1[g];
#pragma unroll
    for (int r = 0; r < 2; ++r) {
        double a = acc[r] + bb;
        o64[(size_t)(r0 + r) * H2 + g] = a;
        o32[(size_t)(r0 + r) * H2 + g] = (float)a;
    }
}

// ---------------------------------------------------------------------------
// dec_full v6: per-pair global atomic replaced by LDS aggregation + one
// global atomicAdd per block (R4: removed the 60-75 us same-line atomic
// serialization floor). Decision math untouched.
// ---------------------------------------------------------------------------
__global__ __launch_bounds__(256, 4) void dec_full(
    const float* __restrict__ U32, const float* __restrict__ W32,
    const float* __restrict__ W2, const float* __restrict__ b2,
    float* __restrict__ dec_out, int* __restrict__ count, int* __restrict__ list)
{
    __shared__ __align__(16) float Us[16][68];    // [i][g-chunk 64]
    __shared__ __align__(16) float Ws[32][68];    // [j][g-chunk 64]
    __shared__ __align__(16) float gvs[H2];
    __shared__ int lbuf[512];
    __shared__ int lcnt, lbase;
    int bid = blockIdx.x;            // b(2) x it(32) x jt(16)
    int b  = bid >> 9;
    int i0 = ((bid >> 4) & 31) * 16;
    int j0 = (bid & 15) * 32;
    int t = threadIdx.x;
    gvs[t] = W2[t * 2 + 1] - W2[t * 2];
    if (t == 0) lcnt = 0;
    float bias = b2[1] - b2[0];
    int ti = t >> 4, tj = t & 15;    // i = i0+ti; j in {j0+tj, j0+tj+16}
    float acc0 = 0.f, acc1 = 0.f;
    for (int gc = 0; gc < H2; gc += 64) {
        __syncthreads();
        {   // stage U: 16 rows x 16 float4, 1/thread, coalesced
            int ui = t >> 4, gq = t & 15;
            *(float4*)&Us[ui][gq * 4] =
                *(const float4*)(U32 + ((size_t)(b * LQ) + i0 + ui) * H2 + gc + gq * 4);
        }
        {   // stage W: 32 rows x 16 float4, 2/thread, coalesced
            int wj = t >> 3, gq = t & 7;
            const float* src = W32 + ((size_t)(b * LQ) + j0 + wj) * H2 + gc;
            *(float4*)&Ws[wj][gq * 4] = *(const float4*)(src + gq * 4);
            *(float4*)&Ws[wj][(gq + 8) * 4] = *(const float4*)(src + (gq + 8) * 4);
        }
        __syncthreads();
        float4 u_c  = *(const float4*)&Us[ti][0];
        float4 gv_c = *(const float4*)&gvs[gc];
        float4 wA_c = *(const float4*)&Ws[tj][0];
        float4 wB_c = *(const float4*)&Ws[tj + 16][0];
#pragma unroll 5
        for (int gg = 0; gg < 60; gg += 4) {
            float4 u_n  = *(const float4*)&Us[ti][gg + 4];
            float4 gv_n = *(const float4*)&gvs[gc + gg + 4];
            float4 wA_n = *(const float4*)&Ws[tj][gg + 4];
            float4 wB_n = *(const float4*)&Ws[tj + 16][gg + 4];
            acc0 = fmaf(fmaxf(u_c.x + wA_c.x, 0.f), gv_c.x, acc0);
            acc1 = fmaf(fmaxf(u_c.x + wB_c.x, 0.f), gv_c.x, acc1);
            acc0 = fmaf(fmaxf(u_c.y + wA_c.y, 0.f), gv_c.y, acc0);
            acc1 = fmaf(fmaxf(u_c.y + wB_c.y, 0.f), gv_c.y, acc1);
            acc0 = fmaf(fmaxf(u_c.z + wA_c.z, 0.f), gv_c.z, acc0);
            acc1 = fmaf(fmaxf(u_c.z + wB_c.z, 0.f), gv_c.z, acc1);
            acc0 = fmaf(fmaxf(u_c.w + wA_c.w, 0.f), gv_c.w, acc0);
            acc1 = fmaf(fmaxf(u_c.w + wB_c.w, 0.f), gv_c.w, acc1);
            u_c = u_n; gv_c = gv_n; wA_c = wA_n; wB_c = wB_n;
        }
        acc0 = fmaf(fmaxf(u_c.x + wA_c.x, 0.f), gv_c.x, acc0);
        acc1 = fmaf(fmaxf(u_c.x + wB_c.x, 0.f), gv_c.x, acc1);
        acc0 = fmaf(fmaxf(u_c.y + wA_c.y, 0.f), gv_c.y, acc0);
        acc1 = fmaf(fmaxf(u_c.y + wB_c.y, 0.f), gv_c.y, acc1);
        acc0 = fmaf(fmaxf(u_c.z + wA_c.z, 0.f), gv_c.z, acc0);
        acc1 = fmaf(fmaxf(u_c.z + wB_c.z, 0.f), gv_c.z, acc1);
        acc0 = fmaf(fmaxf(u_c.w + wA_c.w, 0.f), gv_c.w, acc0);
        acc1 = fmaf(fmaxf(u_c.w + wB_c.w, 0.f), gv_c.w, acc1);
    }
    int row = b * LQ + i0 + ti;
    float gA = acc0 + bias, gB = acc1 + bias;
    int jA = j0 + tj, jB = j0 + tj + 16;
    dec_out[(size_t)row * LQ + jA] = gA > 0.f ? 1.f : 0.f;
    dec_out[(size_t)row * LQ + jB] = gB > 0.f ? 1.f : 0.f;
    if (fabsf(gA) < 2e-2f) { int lx = atomicAdd(&lcnt, 1); lbuf[lx] = (row << 9) | jA; }
    if (fabsf(gB) < 2e-2f) { int lx = atomicAdd(&lcnt, 1); lbuf[lx] = (row << 9) | jB; }
    __syncthreads();
    if (t == 0 && lcnt > 0) lbase = atomicAdd(count, lcnt);
    __syncthreads();
    for (int x = t; x < lcnt; x += 256) {
        int ix = lbase + x;
        if (ix < CAP) list[ix] = lbuf[x];
    }
}

// ---------------------------------------------------------------------------
// Exact fp64 gap for every flagged pair; writes fp64-sign decision.
// ---------------------------------------------------------------------------
__global__ __launch_bounds__(256) void gap64_kernel(
    const double* __restrict__ U64, const double* __restrict__ W64,
    const float* __restrict__ W2, const float* __restrict__ b2,
    const int* __restrict__ count, const int* __restrict__ list,
    float* __restrict__ dec_out)
{
    int n = *count; if (n > CAP) n = CAP;
    int gw = (blockIdx.x * 256 + threadIdx.x) >> 6;
    int lane = threadIdx.x & 63;
    int nw = (gridDim.x * 256) >> 6;
    for (int idx = gw; idx < n; idx += nw) {
        int pij = list[idx];
        int j = pij & (LQ - 1);
        int row = pij >> 9;
        int b = row >> 9;
        const double* u = U64 + (size_t)row * H2;
        const double* w = W64 + ((size_t)(b * LQ) + j) * H2;
        double acc = 0.0;
        for (int g = lane; g < H2; g += 64) {
            double tv = u[g] + w[g];
            tv = tv > 0.0 ? tv : 0.0;
            acc = fma(tv, (double)W2[g * 2 + 1] - (double)W2[g * 2 + 0], acc);
        }
#pragma unroll
        for (int off = 32; off; off >>= 1) acc += __shfl_xor(acc, off, 64);
        if (lane == 0) {
            acc += (double)b2[1] - (double)b2[0];
            dec_out[(size_t)row * LQ + j] = acc > 0.0 ? 1.f : 0.f;
        }
    }
}

// ---------------------------------------------------------------------------
// Fused attention v3: 8i x 8j register microtile, wave-uniform A-operand.
// R4 profile: VALUBusy 33% = LDS-pipe/intensity bound (4x4 tile: 2 b128 per
// 16 FMA; PV: 3 reads per 8 FMA). v3: wave = 8 i-rows (ig), lane owns j-quads
// {4*lane, 256+4*lane}. QK per kk: 2 broadcast b128 (qT, wave-uniform addr)
// + 2 conflict-free full b128 (kT) -> 64 FMA. kT staged per 16-kk chunk
// [16][516] (2-way-free transpose writes). Two-quad j split avoids the
// 16-bank aliasing of a contiguous 8-float read. Softmax width-64 in-wave.
// PV: Pt[64][36] (transposed P, broadcast reads) + Vs[64][68]; thread =
// (ig, d-col): 1 spread b32 + 2 broadcast b128 per 8 FMA.
// ---------------------------------------------------------------------------
#define QK_R(ar, sa, sb)                                   \
    sa.x = fmaf(ar, b0.x, sa.x); sa.y = fmaf(ar, b0.y, sa.y); \
    sa.z = fmaf(ar, b0.z, sa.z); sa.w = fmaf(ar, b0.w, sa.w); \
    sb.x = fmaf(ar, b1.x, sb.x); sb.y = fmaf(ar, b1.y, sb.y); \
    sb.z = fmaf(ar, b1.z, sb.z); sb.w = fmaf(ar, b1.w, sb.w);

#define SM_ROW(sa, sb, r) {                                                     \
    size_t dro = ((size_t)(b * LQ) + i0 + ig * 8 + r) * LQ + lane * 4;          \
    float4 m0 = *(const float4*)&dec[dro];                                      \
    float4 m1 = *(const float4*)&dec[dro + 256];                                \
    sa.x = m0.x != 0.f ? sa.x * 0.125f : NEG_INF;                               \
    sa.y = m0.y != 0.f ? sa.y * 0.125f : NEG_INF;                               \
    sa.z = m0.z != 0.f ? sa.z * 0.125f : NEG_INF;                               \
    sa.w = m0.w != 0.f ? sa.w * 0.125f : NEG_INF;                               \
    sb.x = m1.x != 0.f ? sb.x * 0.125f : NEG_INF;                               \
    sb.y = m1.y != 0.f ? sb.y * 0.125f : NEG_INF;                               \
    sb.z = m1.z != 0.f ? sb.z * 0.125f : NEG_INF;                               \
    sb.w = m1.w != 0.f ? sb.w * 0.125f : NEG_INF;                               \
    float mx = fmaxf(fmaxf(fmaxf(sa.x, sa.y), fmaxf(sa.z, sa.w)),              \
                     fmaxf(fmaxf(sb.x, sb.y), fmaxf(sb.z, sb.w)));              \
    _Pragma("unroll")                                                            \
    for (int off = 1; off < 64; off <<= 1) mx = fmaxf(mx, __shfl_xor(mx, off, 64)); \
    sa.x = __expf(sa.x - mx); sa.y = __expf(sa.y - mx);                         \
    sa.z = __expf(sa.z - mx); sa.w = __expf(sa.w - mx);                         \
    sb.x = __expf(sb.x - mx); sb.y = __expf(sb.y - mx);                         \
    sb.z = __expf(sb.z - mx); sb.w = __expf(sb.w - mx);                         \
    float sm = sa.x + sa.y + sa.z + sa.w + sb.x + sb.y + sb.z + sb.w;           \
    _Pragma("unroll")                                                            \
    for (int off = 1; off < 64; off <<= 1) sm += __shfl_xor(sm, off, 64);       \
    float inv = 1.f / sm;                                                       \
    sa.x *= inv; sa.y *= inv; sa.z *= inv; sa.w *= inv;                         \
    sb.x *= inv; sb.y *= inv; sb.z *= inv; sb.w *= inv;                         \
    size_t aro = ((size_t)bn * LQ + i0 + ig * 8 + r) * LQ + lane * 4;           \
    *(float4*)&attn[aro] = sa;                                                  \
    *(float4*)&attn[aro + 256] = sb;                                            \
}

#define PT_W(s0, s1, s2, s3, s4, s5, s6, s7) do {                               \
    int jl4 = (lane & 15) * 4;                                                  \
    *(float4*)&Pt[(jl4 + 0) * 36 + ig * 8    ] = make_float4(s0.x, s1.x, s2.x, s3.x); \
    *(float4*)&Pt[(jl4 + 0) * 36 + ig * 8 + 4] = make_float4(s4.x, s5.x, s6.x, s7.x); \
    *(float4*)&Pt[(jl4 + 1) * 36 + ig * 8    ] = make_float4(s0.y, s1.y, s2.y, s3.y); \
    *(float4*)&Pt[(jl4 + 1) * 36 + ig * 8 + 4] = make_float4(s4.y, s5.y, s6.y, s7.y); \
    *(float4*)&Pt[(jl4 + 2) * 36 + ig * 8    ] = make_float4(s0.z, s1.z, s2.z, s3.z); \
    *(float4*)&Pt[(jl4 + 2) * 36 + ig * 8 + 4] = make_float4(s4.z, s5.z, s6.z, s7.z); \
    *(float4*)&Pt[(jl4 + 3) * 36 + ig * 8    ] = make_float4(s0.w, s1.w, s2.w, s3.w); \
    *(float4*)&Pt[(jl4 + 3) * 36 + ig * 8 + 4] = make_float4(s4.w, s5.w, s6.w, s7.w); \
} while (0)

__global__ __launch_bounds__(256) void fused_attn(
    const float* __restrict__ q, const float* __restrict__ k,
    const float* __restrict__ v, const float* __restrict__ dec,
    float* __restrict__ attn, float* __restrict__ out)
{
    __shared__ __align__(16) float smem[10560];   // 42.2 KB, phase-overlaid
    float* qT = smem;            // [64 kk][36]      (QK phase)
    float* kT = smem + 2304;     // [16 kk][516]     (QK phase, per chunk)
    float* Pt = smem;            // [64 j][36]       (PV phase)
    float* Vs = smem + 2304;     // [64 j][68]       (PV phase)
    int bid = blockIdx.x;
    int bn = bid >> 4;
    int i0 = (bid & 15) * 32;
    int b = bn >> 4;
    int t = threadIdx.x;
    int ig = t >> 6;             // wave id: i-rows i0 + ig*8 + (0..7)
    int lane = t & 63;           // j-quads {4*lane, 256+4*lane}

    {   // stage qT (transpose): i = t>>3 (0..31), kkq = (t&7)+8*it
        int qi = t >> 3;
        const float* src = q + ((size_t)bn * LQ + i0 + qi) * DKk;
#pragma unroll
        for (int it = 0; it < 2; ++it) {
            int kkq = (t & 7) + it * 8;
            float4 t4 = *(const float4*)(src + kkq * 4);
            qT[(kkq * 4 + 0) * 36 + qi] = t4.x;
            qT[(kkq * 4 + 1) * 36 + qi] = t4.y;
            qT[(kkq * 4 + 2) * 36 + qi] = t4.z;
            qT[(kkq * 4 + 3) * 36 + qi] = t4.w;
        }
    }

    float4 sA0 = {}, sA1 = {}, sA2 = {}, sA3 = {}, sA4 = {}, sA5 = {}, sA6 = {}, sA7 = {};
    float4 sB0 = {}, sB1 = {}, sB2 = {}, sB3 = {}, sB4 = {}, sB5 = {}, sB6 = {}, sB7 = {};

    for (int kc = 0; kc < 4; ++kc) {
        __syncthreads();
        {   // stage kT chunk: 16 kk x 512 j, transposed. q = t&3, j = (t>>2)+64*it
            int qq = t & 3;
            int jb = t >> 2;
#pragma unroll
            for (int it = 0; it < 8; ++it) {
                int j = jb + it * 64;
                float4 t4 = *(const float4*)(k + ((size_t)bn * LQ + j) * DKk + kc * 16 + qq * 4);
                kT[(qq * 4 + 0) * 516 + j] = t4.x;
                kT[(qq * 4 + 1) * 516 + j] = t4.y;
                kT[(qq * 4 + 2) * 516 + j] = t4.z;
                kT[(qq * 4 + 3) * 516 + j] = t4.w;
            }
        }
        __syncthreads();
#pragma unroll
        for (int kk = 0; kk < 16; ++kk) {
            float4 a0 = *(const float4*)&qT[(kc * 16 + kk) * 36 + ig * 8];
            float4 a1 = *(const float4*)&qT[(kc * 16 + kk) * 36 + ig * 8 + 4];
            float4 b0 = *(const float4*)&kT[kk * 516 + lane * 4];
            float4 b1 = *(const float4*)&kT[kk * 516 + 256 + lane * 4];
            QK_R(a0.x, sA0, sB0); QK_R(a0.y, sA1, sB1);
            QK_R(a0.z, sA2, sB2); QK_R(a0.w, sA3, sB3);
            QK_R(a1.x, sA4, sB4); QK_R(a1.y, sA5, sB5);
            QK_R(a1.z, sA6, sB6); QK_R(a1.w, sA7, sB7);
        }
    }

    // mask + softmax (width-64, rows fully in-wave) + attn write
    SM_ROW(sA0, sB0, 0); SM_ROW(sA1, sB1, 1); SM_ROW(sA2, sB2, 2); SM_ROW(sA3, sB3, 3);
    SM_ROW(sA4, sB4, 4); SM_ROW(sA5, sB5, 5); SM_ROW(sA6, sB6, 6); SM_ROW(sA7, sB7, 7);

    // ---- PV over eight 64-j chunks ----
    float o[8] = {};
    for (int c = 0; c < 8; ++c) {
        __syncthreads();
        if ((lane >> 4) == (c & 3)) {   // this lane's j-quad is in chunk c
            if (c < 4) { PT_W(sA0, sA1, sA2, sA3, sA4, sA5, sA6, sA7); }
            else       { PT_W(sB0, sB1, sB2, sB3, sB4, sB5, sB6, sB7); }
        }
        {   // stage Vs: j = t>>2, dq = (t&3)+4*it
            int vj = t >> 2;
#pragma unroll
            for (int it = 0; it < 4; ++it) {
                int dq = (t & 3) + it * 4;
                *(float4*)&Vs[vj * 68 + dq * 4] =
                    *(const float4*)(v + ((size_t)bn * LQ + c * 64 + vj) * DVv + dq * 4);
            }
        }
        __syncthreads();
#pragma unroll 8
        for (int jj = 0; jj < 64; ++jj) {
            float4 pa = *(const float4*)&Pt[jj * 36 + ig * 8];
            float4 pb = *(const float4*)&Pt[jj * 36 + ig * 8 + 4];
            float vv = Vs[jj * 68 + lane];
            o[0] = fmaf(pa.x, vv, o[0]); o[1] = fmaf(pa.y, vv, o[1]);
            o[2] = fmaf(pa.z, vv, o[2]); o[3] = fmaf(pa.w, vv, o[3]);
            o[4] = fmaf(pb.x, vv, o[4]); o[5] = fmaf(pb.y, vv, o[5]);
            o[6] = fmaf(pb.z, vv, o[6]); o[7] = fmaf(pb.w, vv, o[7]);
        }
    }
#pragma unroll
    for (int r = 0; r < 8; ++r)
        out[((size_t)bn * LQ + i0 + ig * 8 + r) * DVv + lane] = o[r];
}

// ---------------------------------------------------------------------------
extern "C" void kernel_launch(void* const* d_in, const int* in_sizes, int n_in,
                              void* d_out, int out_size, void* d_ws, size_t ws_size,
                              hipStream_t stream)
{
    const float* q  = (const float*)d_in[0];
    const float* k  = (const float*)d_in[1];
    const float* v  = (const float*)d_in[2];
    const float* d0 = (const float*)d_in[3];
    const float* d1 = (const float*)d_in[4];
    const float* W1 = (const float*)d_in[5];
    const float* b1 = (const float*)d_in[6];
    const float* W2 = (const float*)d_in[7];
    const float* b2 = (const float*)d_in[8];

    float* out  = (float*)d_out;                                  // [2,16,512,64]
    float* attn = out + (size_t)BB * NN * LQ * DVv;               // [2,16,512,512]
    float* dec  = attn + (size_t)BB * NN * LQ * LQ;               // [2,1,512,512]

    // Scratch inside the attn region (32 MB); fully consumed before
    // fused_attn overwrites every attn element (same stream => ordered).
    char* scratch = (char*)attn;
    double* U64 = (double*)(scratch);                             // 0..2 MB
    double* W64 = (double*)(scratch + (2u << 20));                // 2..4 MB
    float*  U32 = (float*) (scratch + (4u << 20));                // 4..5 MB
    float*  W32 = (float*) (scratch + (5u << 20));                // 5..6 MB
    int* count  = (int*)   (scratch + (6u << 20));                // 4 B
    int* list   = (int*)   (scratch + (6u << 20) + 4096);         // 512 KB

    mlp_stage1<<<1024, 256, 0, stream>>>(d0, d1, W1, b1, U64, W64, U32, W32, count);
    dec_full<<<1024, 256, 0, stream>>>(U32, W32, W2, b2, dec, count, list);
    gap64_kernel<<<256, 256, 0, stream>>>(U64, W64, W2, b2, count, list, dec);
    fused_attn<<<512, 256, 0, stream>>>(q, k, v, dec, attn, out);
}